// Round 5
// baseline (737.725 us; speedup 1.0000x reference)
//
#include <hip/hip_runtime.h>
#include <hip/hip_bf16.h>
#include <cstddef>
#include <cstdint>

#define TPB 256
#define HID 128
#define GATD 512
#define HEADS 4

typedef __attribute__((ext_vector_type(8))) short bf16x8;
typedef __attribute__((ext_vector_type(4))) float f32x4;

__device__ __forceinline__ float lrelu02(float x) { return x > 0.0f ? x : 0.2f * x; }

__device__ __forceinline__ unsigned short f2bf_rn(float f) {
  uint32_t u = __float_as_uint(f);
  u += 0x7fff + ((u >> 16) & 1);
  return (unsigned short)(u >> 16);
}
__device__ __forceinline__ float bf2f(unsigned short h) {
  return __uint_as_float(((uint32_t)h) << 16);
}
__device__ __forceinline__ float bflo(uint32_t u) { return __uint_as_float(u << 16); }
__device__ __forceinline__ float bfhi(uint32_t u) { return __uint_as_float(u & 0xffff0000u); }

#define GLD16(gsrc, ldst)                                                          \
  __builtin_amdgcn_global_load_lds(                                                \
      (const __attribute__((address_space(1))) unsigned int*)(gsrc),               \
      (__attribute__((address_space(3))) unsigned int*)(ldst), 16, 0, 0)

// ---------------- utility ----------------
__global__ void k_zero(int* __restrict__ p, int n) {
  int i = blockIdx.x * blockDim.x + threadIdx.x;
  if (i < n) p[i] = 0;
}

// ---------------- CSR build ----------------
__global__ void k_hist(const int* __restrict__ dst, int* __restrict__ cnt, int E) {
  int i = blockIdx.x * blockDim.x + threadIdx.x;
  if (i < E) atomicAdd(&cnt[dst[i]], 1);
}

__global__ void k_dinv(const int* __restrict__ cnt, float* __restrict__ dinv, int n) {
  int i = blockIdx.x * blockDim.x + threadIdx.x;
  if (i < n) dinv[i] = rsqrtf((float)(cnt[i] + 1));  // +1 = self loop
}

__global__ __launch_bounds__(1024) void k_scan(const int* __restrict__ cnt,
                                               int* __restrict__ rowp, int n) {
  __shared__ int sm[1024];
  __shared__ int carry;
  const int tid = threadIdx.x;
  if (tid == 0) carry = 0;
  __syncthreads();
  for (int base = 0; base < n; base += 1024) {
    int idx = base + tid;
    int v = (idx < n) ? cnt[idx] : 0;
    sm[tid] = v;
    __syncthreads();
    for (int off = 1; off < 1024; off <<= 1) {
      int t = (tid >= off) ? sm[tid - off] : 0;
      __syncthreads();
      sm[tid] += t;
      __syncthreads();
    }
    int incl = sm[tid];
    int c = carry;
    if (idx < n) rowp[idx] = c + incl - v;  // exclusive
    __syncthreads();
    if (tid == 1023) carry = c + sm[1023];
    __syncthreads();
  }
  if (tid == 0) rowp[n] = carry;
}

__global__ void k_fill(const int* __restrict__ src, const int* __restrict__ dst,
                       const int* __restrict__ rowp, int* __restrict__ cur,
                       int* __restrict__ colsrc, int E) {
  int i = blockIdx.x * blockDim.x + threadIdx.x;
  if (i < E) {
    int d = dst[i];
    int pos = rowp[d] + atomicAdd(&cur[d], 1);
    colsrc[pos] = src[i];
  }
}

// ---------------- one-time splits ----------------
__global__ void k_splitx(const float* __restrict__ x, unsigned short* __restrict__ xh,
                         unsigned short* __restrict__ xl, long n) {
  long i = (long)blockIdx.x * blockDim.x + threadIdx.x;
  if (i < n) {
    float v = x[i];
    unsigned short h = f2bf_rn(v);
    xh[i] = h;
    xl[i] = f2bf_rn(v - bf2f(h));
  }
}

// W[K,NC] -> WhT/WlT [NC,K] (transposed hi/lo planes)
__global__ void k_splitwt(const float* __restrict__ W, unsigned short* __restrict__ WhT,
                          unsigned short* __restrict__ WlT, int K, int NC) {
  int t = blockIdx.x * blockDim.x + threadIdx.x;
  if (t < K * NC) {
    int k = t / NC, n = t % NC;
    float v = W[t];
    unsigned short h = f2bf_rn(v);
    WhT[(size_t)n * K + k] = h;
    WlT[(size_t)n * K + k] = f2bf_rn(v - bf2f(h));
  }
}

// ---------------- MFMA GEMM, pre-split bf16 planes, global_load_lds staging ----------------
// C = act(A @ W + bias), A given as (Ah,Al)[M,K], W as (BhT,BlT)[NC,K] (transposed planes).
// A*B ~= Ah*Bh + Ah*Bl + Al*Bh.  BM=128, BK=32, 4 waves 2x2.
// OUTM: 0 = f32, 1 = bf16, 2 = hi/lo planes (Cv, Cv2)
template <int BN, int WCF, bool RELU, bool BIAS, int OUTM>
__global__ __launch_bounds__(256) void k_gemm2(
    const unsigned short* __restrict__ Ah, const unsigned short* __restrict__ Al,
    const unsigned short* __restrict__ BhT, const unsigned short* __restrict__ BlT,
    const float* __restrict__ bias, void* __restrict__ Cv, void* __restrict__ Cv2,
    int M, int K, int NC) {
  constexpr int BM = 128;
  __shared__ alignas(16) unsigned short As[2][4][BM][8];
  __shared__ alignas(16) unsigned short Bs[2][4][BN][8];
  const int tid = threadIdx.x;
  const int lane = tid & 63;
  const int wid = tid >> 6;
  const int wr = wid >> 1, wc = wid & 1;
  const int m0 = blockIdx.x * BM;
  const int n0 = blockIdx.y * BN;
  const int fr = lane & 15, g = lane >> 4;

  f32x4 acc[4][WCF];
#pragma unroll
  for (int mr = 0; mr < 4; ++mr)
#pragma unroll
    for (int nc = 0; nc < WCF; ++nc) acc[mr][nc] = (f32x4){0.f, 0.f, 0.f, 0.f};

  constexpr int ARUNS = 16;                 // 2 planes * 4 kg * 2 row-halves
  constexpr int BRUNS = 8 * (BN / 64);      // 2 planes * 4 kg * (BN/64)
  constexpr int RUNS = ARUNS + BRUNS;

  for (int k0 = 0; k0 < K; k0 += 32) {
    // ---- stage: each run = 64 lanes x 16B -> one [kg][64 rows] slab ----
    for (int rr = wid; rr < RUNS; rr += 4) {
      if (rr < ARUNS) {
        const int p = rr & 1, kg = (rr >> 1) & 3, rb = rr >> 3;
        const int row = rb * 64 + lane;
        const unsigned short* s =
            (p ? Al : Ah) + (size_t)(m0 + row) * K + k0 + kg * 8;
        if (m0 + row < M) GLD16(s, &As[p][kg][rb * 64][0]);
      } else {
        const int q = rr - ARUNS;
        const int p = q & 1, kg = (q >> 1) & 3, rb = q >> 3;
        const int col = rb * 64 + lane;
        const unsigned short* s =
            (p ? BlT : BhT) + (size_t)(n0 + col) * K + k0 + kg * 8;
        GLD16(s, &Bs[p][kg][rb * 64][0]);
      }
    }
    __syncthreads();
    // ---- frags + MFMA ----
    bf16x8 ah[4], al[4], bh[WCF], bl[WCF];
#pragma unroll
    for (int mr = 0; mr < 4; ++mr) {
      const int row = wr * 64 + mr * 16 + fr;
      ah[mr] = *(const bf16x8*)&As[0][g][row][0];
      al[mr] = *(const bf16x8*)&As[1][g][row][0];
    }
#pragma unroll
    for (int nc = 0; nc < WCF; ++nc) {
      const int col = wc * WCF * 16 + nc * 16 + fr;
      bh[nc] = *(const bf16x8*)&Bs[0][g][col][0];
      bl[nc] = *(const bf16x8*)&Bs[1][g][col][0];
    }
#pragma unroll
    for (int mr = 0; mr < 4; ++mr)
#pragma unroll
      for (int nc = 0; nc < WCF; ++nc) {
        acc[mr][nc] = __builtin_amdgcn_mfma_f32_16x16x32_bf16(ah[mr], bh[nc], acc[mr][nc], 0, 0, 0);
        acc[mr][nc] = __builtin_amdgcn_mfma_f32_16x16x32_bf16(ah[mr], bl[nc], acc[mr][nc], 0, 0, 0);
        acc[mr][nc] = __builtin_amdgcn_mfma_f32_16x16x32_bf16(al[mr], bh[nc], acc[mr][nc], 0, 0, 0);
      }
    __syncthreads();
  }
  // ---- epilogue ----
#pragma unroll
  for (int mr = 0; mr < 4; ++mr) {
#pragma unroll
    for (int nc = 0; nc < WCF; ++nc) {
      const int col = n0 + wc * WCF * 16 + nc * 16 + fr;
      const float bv = BIAS ? bias[col] : 0.f;
#pragma unroll
      for (int r = 0; r < 4; ++r) {
        const int grow = m0 + wr * 64 + mr * 16 + g * 4 + r;
        if (grow < M) {
          float v = acc[mr][nc][r] + bv;
          if (RELU) v = fmaxf(v, 0.f);
          const size_t idx = (size_t)grow * NC + col;
          if (OUTM == 0) {
            ((float*)Cv)[idx] = v;
          } else if (OUTM == 1) {
            ((unsigned short*)Cv)[idx] = f2bf_rn(v);
          } else {
            unsigned short h = f2bf_rn(v);
            ((unsigned short*)Cv)[idx] = h;
            ((unsigned short*)Cv2)[idx] = f2bf_rn(v - bf2f(h));
          }
        }
      }
    }
  }
}

// ---------------- GCN aggregate + bias + LN + ReLU (+residual, +fused GAT logits) ----------------
// Output written as hi/lo bf16 planes. L2: residual from planes, a_s/a_d from exact fp32 values.
template <bool L2>
__global__ __launch_bounds__(256) void k_gcn_agg(
    const float* __restrict__ xw, const float* __restrict__ dinv,
    const int* __restrict__ rowp, const int* __restrict__ colsrc,
    const float* __restrict__ bias, const float* __restrict__ gamma,
    const float* __restrict__ beta,
    const unsigned short* __restrict__ resh, const unsigned short* __restrict__ resl,
    unsigned short* __restrict__ oh, unsigned short* __restrict__ ol,
    const float* __restrict__ waT, float* __restrict__ a_s, float* __restrict__ a_d,
    int n) {
  __shared__ float w[8][HID];
  if (L2) {
    for (int t = threadIdx.x; t < 8 * HID; t += 256) ((float*)w)[t] = waT[t];
    __syncthreads();
  }
  const int lane = threadIdx.x & 63;
  const int i = blockIdx.x * 4 + (threadIdx.x >> 6);
  if (i >= n) return;
  const float di = dinv[i];
  const int c = lane * 2;
  float2 v = *(const float2*)(xw + (size_t)i * HID + c);
  float a0 = v.x * di * di, a1 = v.y * di * di;  // self loop
  const int e0 = rowp[i], e1 = rowp[i + 1];
  for (int j = e0; j < e1; ++j) {
    int s = colsrc[j];
    float wgt = dinv[s] * di;
    float2 u = *(const float2*)(xw + (size_t)s * HID + c);
    a0 = fmaf(u.x, wgt, a0);
    a1 = fmaf(u.y, wgt, a1);
  }
  a0 += bias[c];
  a1 += bias[c + 1];
  float s1 = a0 + a1, s2 = a0 * a0 + a1 * a1;
#pragma unroll
  for (int m = 32; m >= 1; m >>= 1) {
    s1 += __shfl_xor(s1, m);
    s2 += __shfl_xor(s2, m);
  }
  float mu = s1 * (1.0f / HID);
  float var = s2 * (1.0f / HID) - mu * mu;
  float rstd = rsqrtf(var + 1e-5f);
  float y0 = fmaxf((a0 - mu) * rstd * gamma[c] + beta[c], 0.0f);
  float y1 = fmaxf((a1 - mu) * rstd * gamma[c + 1] + beta[c + 1], 0.0f);
  if (L2) {
    uint32_t rh = *(const uint32_t*)(resh + (size_t)i * HID + c);
    uint32_t rl = *(const uint32_t*)(resl + (size_t)i * HID + c);
    y0 += bflo(rh) + bflo(rl);
    y1 += bfhi(rh) + bfhi(rl);
  }
  // write hi/lo planes
  unsigned short ph0 = f2bf_rn(y0), ph1 = f2bf_rn(y1);
  uint32_t hw = (uint32_t)ph0 | ((uint32_t)ph1 << 16);
  uint32_t lw = (uint32_t)f2bf_rn(y0 - bf2f(ph0)) |
                ((uint32_t)f2bf_rn(y1 - bf2f(ph1)) << 16);
  *(uint32_t*)(oh + (size_t)i * HID + c) = hw;
  *(uint32_t*)(ol + (size_t)i * HID + c) = lw;
  if (L2) {
    // fused GAT logits from exact fp32 x2 values
    float p[8];
#pragma unroll
    for (int h = 0; h < 8; ++h) p[h] = y0 * w[h][c] + y1 * w[h][c + 1];
#pragma unroll
    for (int m = 32; m >= 1; m >>= 1) {
#pragma unroll
      for (int h = 0; h < 8; ++h) p[h] += __shfl_xor(p[h], m);
    }
    if (lane == 0) {
      a_s[i * 4 + 0] = p[0]; a_s[i * 4 + 1] = p[1];
      a_s[i * 4 + 2] = p[2]; a_s[i * 4 + 3] = p[3];
      a_d[i * 4 + 0] = p[4]; a_d[i * 4 + 1] = p[5];
      a_d[i * 4 + 2] = p[6]; a_d[i * 4 + 3] = p[7];
    }
  }
}

// ---------------- fold Wgat into attention vectors: waT[p][k], p<4: src head p; p>=4: dst ----------------
__global__ __launch_bounds__(256) void k_wprep(const float* __restrict__ Wgat,
                                               const float* __restrict__ att_src,
                                               const float* __restrict__ att_dst,
                                               float* __restrict__ waT) {
  int t = blockIdx.x * blockDim.x + threadIdx.x;  // 0..1023
  if (t >= 1024) return;
  int p = t >> 7, k = t & 127;
  int h = p & 3;
  const float* av = (p < 4 ? att_src : att_dst) + h * HID;
  const float* wrow = Wgat + (size_t)k * GATD + h * HID;
  float s = 0.f;
#pragma unroll 4
  for (int c = 0; c < HID; ++c) s = fmaf(wrow[c], av[c], s);
  waT[t] = s;
}

// ---------------- GAT softmax-aggregate (wave/node), bf16 table, plane output ----------------
__global__ __launch_bounds__(256) void k_gat_agg(const unsigned short* __restrict__ xwgb,
                                                 const float* __restrict__ a_s,
                                                 const float* __restrict__ a_d,
                                                 const int* __restrict__ rowp,
                                                 const int* __restrict__ colsrc,
                                                 const float* __restrict__ bias,
                                                 unsigned short* __restrict__ gath,
                                                 unsigned short* __restrict__ gatl,
                                                 int n) {
  const int lane = threadIdx.x & 63;
  const int i = blockIdx.x * 4 + (threadIdx.x >> 6);
  if (i >= n) return;
  const float4 adv = *(const float4*)(a_d + i * 4);
  const float4 asv = *(const float4*)(a_s + i * 4);
  float es0 = lrelu02(asv.x + adv.x);
  float es1 = lrelu02(asv.y + adv.y);
  float es2 = lrelu02(asv.z + adv.z);
  float es3 = lrelu02(asv.w + adv.w);
  const int e0 = rowp[i], e1 = rowp[i + 1];
  float m0 = es0, m1 = es1, m2 = es2, m3 = es3;
  for (int j = e0 + lane; j < e1; j += 64) {
    int s = colsrc[j];
    const float4 av = *(const float4*)(a_s + s * 4);
    m0 = fmaxf(m0, lrelu02(av.x + adv.x));
    m1 = fmaxf(m1, lrelu02(av.y + adv.y));
    m2 = fmaxf(m2, lrelu02(av.z + adv.z));
    m3 = fmaxf(m3, lrelu02(av.w + adv.w));
  }
#pragma unroll
  for (int m = 32; m >= 1; m >>= 1) {
    m0 = fmaxf(m0, __shfl_xor(m0, m));
    m1 = fmaxf(m1, __shfl_xor(m1, m));
    m2 = fmaxf(m2, __shfl_xor(m2, m));
    m3 = fmaxf(m3, __shfl_xor(m3, m));
  }
  float d0 = 0.f, d1 = 0.f, d2 = 0.f, d3 = 0.f;
  for (int j = e0 + lane; j < e1; j += 64) {
    int s = colsrc[j];
    const float4 av = *(const float4*)(a_s + s * 4);
    d0 += __expf(lrelu02(av.x + adv.x) - m0);
    d1 += __expf(lrelu02(av.y + adv.y) - m1);
    d2 += __expf(lrelu02(av.z + adv.z) - m2);
    d3 += __expf(lrelu02(av.w + adv.w) - m3);
  }
#pragma unroll
  for (int m = 32; m >= 1; m >>= 1) {
    d0 += __shfl_xor(d0, m);
    d1 += __shfl_xor(d1, m);
    d2 += __shfl_xor(d2, m);
    d3 += __shfl_xor(d3, m);
  }
  d0 += __expf(es0 - m0);
  d1 += __expf(es1 - m1);
  d2 += __expf(es2 - m2);
  d3 += __expf(es3 - m3);
  const float inv0 = 1.0f / d0, inv1 = 1.0f / d1, inv2 = 1.0f / d2, inv3 = 1.0f / d3;
  const int col = lane * 8;
  const int h = lane >> 4;
  const float mh = (h < 2) ? (h == 0 ? m0 : m1) : (h == 2 ? m2 : m3);
  const float invh = (h < 2) ? (h == 0 ? inv0 : inv1) : (h == 2 ? inv2 : inv3);
  const float adh = (h < 2) ? (h == 0 ? adv.x : adv.y) : (h == 2 ? adv.z : adv.w);
  const float esh = (h < 2) ? (h == 0 ? es0 : es1) : (h == 2 ? es2 : es3);
  const float aself = __expf(esh - mh) * invh;
  uint4 u = *(const uint4*)(xwgb + (size_t)i * GATD + col);
  float4 acc0 = make_float4(bflo(u.x) * aself, bfhi(u.x) * aself,
                            bflo(u.y) * aself, bfhi(u.y) * aself);
  float4 acc1 = make_float4(bflo(u.z) * aself, bfhi(u.z) * aself,
                            bflo(u.w) * aself, bfhi(u.w) * aself);
  for (int j = e0; j < e1; ++j) {
    int s = colsrc[j];
    float al = __expf(lrelu02(a_s[s * 4 + h] + adh) - mh) * invh;
    uint4 w = *(const uint4*)(xwgb + (size_t)s * GATD + col);
    acc0.x = fmaf(bflo(w.x), al, acc0.x); acc0.y = fmaf(bfhi(w.x), al, acc0.y);
    acc0.z = fmaf(bflo(w.y), al, acc0.z); acc0.w = fmaf(bfhi(w.y), al, acc0.w);
    acc1.x = fmaf(bflo(w.z), al, acc1.x); acc1.y = fmaf(bfhi(w.z), al, acc1.y);
    acc1.z = fmaf(bflo(w.w), al, acc1.z); acc1.w = fmaf(bfhi(w.w), al, acc1.w);
  }
  const float4* bp = (const float4*)(bias + col);
  float4 b0 = bp[0], b1 = bp[1];
  float vv[8] = {acc0.x + b0.x, acc0.y + b0.y, acc0.z + b0.z, acc0.w + b0.w,
                 acc1.x + b1.x, acc1.y + b1.y, acc1.z + b1.z, acc1.w + b1.w};
  uint32_t hv[4], lv[4];
#pragma unroll
  for (int q = 0; q < 4; ++q) {
    unsigned short ha = f2bf_rn(vv[2 * q]), hb = f2bf_rn(vv[2 * q + 1]);
    unsigned short la = f2bf_rn(vv[2 * q] - bf2f(ha));
    unsigned short lb = f2bf_rn(vv[2 * q + 1] - bf2f(hb));
    hv[q] = (uint32_t)ha | ((uint32_t)hb << 16);
    lv[q] = (uint32_t)la | ((uint32_t)lb << 16);
  }
  *(uint4*)(gath + (size_t)i * GATD + col) = make_uint4(hv[0], hv[1], hv[2], hv[3]);
  *(uint4*)(gatl + (size_t)i * GATD + col) = make_uint4(lv[0], lv[1], lv[2], lv[3]);
}

extern "C" void kernel_launch(void* const* d_in, const int* in_sizes, int n_in,
                              void* d_out, int out_size, void* d_ws, size_t ws_size,
                              hipStream_t stream) {
  const float* x = (const float*)d_in[0];
  const int* ei = (const int*)d_in[1];
  const float* Win = (const float*)d_in[2];
  const float* bin = (const float*)d_in[3];
  const float* Wg1 = (const float*)d_in[4];
  const float* bg1 = (const float*)d_in[5];
  const float* g1g = (const float*)d_in[6];
  const float* g1b = (const float*)d_in[7];
  const float* Wg2 = (const float*)d_in[8];
  const float* bg2 = (const float*)d_in[9];
  const float* g2g = (const float*)d_in[10];
  const float* g2b = (const float*)d_in[11];
  const float* Wgat = (const float*)d_in[12];
  const float* att_s = (const float*)d_in[13];
  const float* att_d = (const float*)d_in[14];
  const float* bgat = (const float*)d_in[15];
  const float* Wao = (const float*)d_in[16];
  const float* bao = (const float*)d_in[17];
  const float* Wout = (const float*)d_in[18];
  const float* bout = (const float*)d_in[19];

  const int N = in_sizes[0] / 256;
  const int E = in_sizes[1] / 2;
  const int* src = ei;
  const int* dst = ei + E;

  // ---- workspace layout (bytes), ~211 MB ----
  char* base = (char*)d_ws;
  size_t off = 0;
  // P region (102.4 MB): xh|xl|h0h|h0l|x1h|x1l ; later gat planes
  unsigned short* xh = (unsigned short*)(base + off);  off += (size_t)N * 256 * 2;
  unsigned short* xl = (unsigned short*)(base + off);  off += (size_t)N * 256 * 2;
  unsigned short* h0h = (unsigned short*)(base + off); off += (size_t)N * HID * 2;
  unsigned short* h0l = (unsigned short*)(base + off); off += (size_t)N * HID * 2;
  unsigned short* x1h = (unsigned short*)(base + off); off += (size_t)N * HID * 2;
  unsigned short* x1l = (unsigned short*)(base + off); off += (size_t)N * HID * 2;
  unsigned short* gath = xh;   // N*512 ushorts == xh+xl   (dead by GAT agg)
  unsigned short* gatl = h0h;  // N*512 ushorts == h0h..x1l (dead by GAT agg)
  float* xw = (float*)(base + off);                    off += (size_t)N * HID * 4;
  unsigned short* x2h = (unsigned short*)(base + off); off += (size_t)N * HID * 2;
  unsigned short* x2l = (unsigned short*)(base + off); off += (size_t)N * HID * 2;
  unsigned short* atth = x2h;  // reuse (x2 planes dead after Wgat GEMM)
  unsigned short* attl = x2l;
  unsigned short* xwgb = (unsigned short*)(base + off); off += (size_t)N * GATD * 2;
  float* dinv = (float*)(base + off);                  off += (size_t)N * 4;
  float* a_s = (float*)(base + off);                   off += (size_t)N * 16;
  float* a_d = (float*)(base + off);                   off += (size_t)N * 16;
  float* waT = (float*)(base + off);                   off += 4096;
  // weight planes (transposed)
  unsigned short *WinTh, *WinTl, *Wg1Th, *Wg1Tl, *Wg2Th, *Wg2Tl;
  unsigned short *WgatTh, *WgatTl, *WaoTh, *WaoTl, *WoutTh, *WoutTl;
  WinTh = (unsigned short*)(base + off);  off += 256 * 128 * 2;
  WinTl = (unsigned short*)(base + off);  off += 256 * 128 * 2;
  Wg1Th = (unsigned short*)(base + off);  off += 128 * 128 * 2;
  Wg1Tl = (unsigned short*)(base + off);  off += 128 * 128 * 2;
  Wg2Th = (unsigned short*)(base + off);  off += 128 * 128 * 2;
  Wg2Tl = (unsigned short*)(base + off);  off += 128 * 128 * 2;
  WgatTh = (unsigned short*)(base + off); off += 128 * 512 * 2;
  WgatTl = (unsigned short*)(base + off); off += 128 * 512 * 2;
  WaoTh = (unsigned short*)(base + off);  off += 512 * 128 * 2;
  WaoTl = (unsigned short*)(base + off);  off += 512 * 128 * 2;
  WoutTh = (unsigned short*)(base + off); off += 128 * 64 * 2;
  WoutTl = (unsigned short*)(base + off); off += 128 * 64 * 2;
  int* rowp = (int*)(base + off);   off += (size_t)(N + 1) * 4;
  int* colsrc = (int*)(base + off); off += (size_t)E * 4;
  int* cnt = (int*)xwgb;  // alias: dead before xwgb is written
  int* cur = cnt + N;

  const int eb = (E + TPB - 1) / TPB;
  const int nb = (N + TPB - 1) / TPB;
  const int zb = (2 * N + TPB - 1) / TPB;
  const int ab = (N + 3) / 4;
  const int gm = (N + 127) / 128;

  // CSR + prep
  k_zero<<<zb, TPB, 0, stream>>>(cnt, 2 * N);
  k_hist<<<eb, TPB, 0, stream>>>(dst, cnt, E);
  k_dinv<<<nb, TPB, 0, stream>>>(cnt, dinv, N);
  k_scan<<<1, 1024, 0, stream>>>(cnt, rowp, N);
  k_fill<<<eb, TPB, 0, stream>>>(src, dst, rowp, cur, colsrc, E);
  k_wprep<<<4, 256, 0, stream>>>(Wgat, att_s, att_d, waT);
  k_splitx<<<(int)(((long)N * 256 + 255) / 256), 256, 0, stream>>>(x, xh, xl, (long)N * 256);
  k_splitwt<<<(256 * 128 + 255) / 256, 256, 0, stream>>>(Win, WinTh, WinTl, 256, 128);
  k_splitwt<<<(128 * 128 + 255) / 256, 256, 0, stream>>>(Wg1, Wg1Th, Wg1Tl, 128, 128);
  k_splitwt<<<(128 * 128 + 255) / 256, 256, 0, stream>>>(Wg2, Wg2Th, Wg2Tl, 128, 128);
  k_splitwt<<<(128 * 512 + 255) / 256, 256, 0, stream>>>(Wgat, WgatTh, WgatTl, 128, 512);
  k_splitwt<<<(512 * 128 + 255) / 256, 256, 0, stream>>>(Wao, WaoTh, WaoTl, 512, 128);
  k_splitwt<<<(128 * 64 + 255) / 256, 256, 0, stream>>>(Wout, WoutTh, WoutTl, 128, 64);

  // h0 = relu(x @ Win + bin) -> planes
  k_gemm2<128, 4, true, true, 2><<<dim3(gm, 1), 256, 0, stream>>>(
      xh, xl, WinTh, WinTl, bin, h0h, h0l, N, 256, 128);
  // GCN layer 1
  k_gemm2<128, 4, false, false, 0><<<dim3(gm, 1), 256, 0, stream>>>(
      h0h, h0l, Wg1Th, Wg1Tl, nullptr, xw, nullptr, N, 128, 128);
  k_gcn_agg<false><<<ab, 256, 0, stream>>>(xw, dinv, rowp, colsrc, bg1, g1g, g1b,
                                           nullptr, nullptr, x1h, x1l,
                                           nullptr, nullptr, nullptr, N);
  // GCN layer 2 (+residual, +fused GAT logits)
  k_gemm2<128, 4, false, false, 0><<<dim3(gm, 1), 256, 0, stream>>>(
      x1h, x1l, Wg2Th, Wg2Tl, nullptr, xw, nullptr, N, 128, 128);
  k_gcn_agg<true><<<ab, 256, 0, stream>>>(xw, dinv, rowp, colsrc, bg2, g2g, g2b,
                                          x1h, x1l, x2h, x2l, waT, a_s, a_d, N);
  // GAT: xwgb = bf16(x2 @ Wgat)
  k_gemm2<128, 4, false, false, 1><<<dim3(gm, 4), 256, 0, stream>>>(
      x2h, x2l, WgatTh, WgatTl, nullptr, xwgb, nullptr, N, 128, 512);
  // softmax-aggregate -> gat planes (overwrites P region)
  k_gat_agg<<<ab, 256, 0, stream>>>(xwgb, a_s, a_d, rowp, colsrc, bgat, gath, gatl, N);
  // att = relu(gat @ Wao + bao) -> planes (overwrites x2 planes)
  k_gemm2<128, 4, true, true, 2><<<dim3(gm, 1), 256, 0, stream>>>(
      gath, gatl, WaoTh, WaoTl, bao, atth, attl, N, 512, 128);
  // out = att @ Wout + bout (fp32)
  k_gemm2<64, 2, false, true, 0><<<dim3(gm, 1), 256, 0, stream>>>(
      atth, attl, WoutTh, WoutTl, bout, d_out, nullptr, N, 128, 64);
}

// Round 6
// 697.700 us; speedup vs baseline: 1.0574x; 1.0574x over previous
//
#include <hip/hip_runtime.h>
#include <hip/hip_bf16.h>
#include <cstddef>
#include <cstdint>

#define TPB 256
#define HID 128
#define GATD 512
#define HEADS 4

typedef __attribute__((ext_vector_type(8))) short bf16x8;
typedef __attribute__((ext_vector_type(4))) float f32x4;

__device__ __forceinline__ float lrelu02(float x) { return x > 0.0f ? x : 0.2f * x; }

__device__ __forceinline__ unsigned short f2bf_rn(float f) {
  uint32_t u = __float_as_uint(f);
  u += 0x7fff + ((u >> 16) & 1);
  return (unsigned short)(u >> 16);
}
__device__ __forceinline__ float bf2f(unsigned short h) {
  return __uint_as_float(((uint32_t)h) << 16);
}
__device__ __forceinline__ float bflo(uint32_t u) { return __uint_as_float(u << 16); }
__device__ __forceinline__ float bfhi(uint32_t u) { return __uint_as_float(u & 0xffff0000u); }

#define GLD16(gsrc, ldst)                                                          \
  __builtin_amdgcn_global_load_lds(                                                \
      (const __attribute__((address_space(1))) unsigned int*)(gsrc),               \
      (__attribute__((address_space(3))) unsigned int*)(ldst), 16, 0, 0)

// ---------------- utility ----------------
__global__ void k_zero(int* __restrict__ p, int n) {
  int i = blockIdx.x * blockDim.x + threadIdx.x;
  if (i < n) p[i] = 0;
}

// ---------------- CSR build ----------------
__global__ void k_hist(const int* __restrict__ dst, int* __restrict__ cnt, int E) {
  int i = blockIdx.x * blockDim.x + threadIdx.x;
  if (i < E) atomicAdd(&cnt[dst[i]], 1);
}

// block-local exclusive scan over 1024 elems/block (256 thr x 4); also emits dinv
__global__ __launch_bounds__(256) void k_scan_blk(const int* __restrict__ cnt,
                                                  int* __restrict__ rowp,
                                                  int* __restrict__ bsum,
                                                  float* __restrict__ dinv, int n) {
  __shared__ int wsum[4];
  const int tid = threadIdx.x, lane = tid & 63, wid = tid >> 6;
  const int base = blockIdx.x * 1024 + tid * 4;
  int v[4];
#pragma unroll
  for (int q = 0; q < 4; ++q) {
    int idx = base + q;
    v[q] = (idx < n) ? cnt[idx] : 0;
    if (idx < n) dinv[idx] = rsqrtf((float)(v[q] + 1));  // +1 self loop
  }
  int s = v[0] + v[1] + v[2] + v[3];
  int sc = s;
#pragma unroll
  for (int off = 1; off < 64; off <<= 1) {
    int t = __shfl_up(sc, off);
    if (lane >= off) sc += t;
  }
  if (lane == 63) wsum[wid] = sc;
  __syncthreads();
  int woff = 0;
#pragma unroll
  for (int w = 0; w < 4; ++w)
    if (w < wid) woff += wsum[w];
  int run = woff + sc - s;  // exclusive within block
#pragma unroll
  for (int q = 0; q < 4; ++q) {
    int idx = base + q;
    if (idx < n) rowp[idx] = run;
    run += v[q];
  }
  if (tid == 255) bsum[blockIdx.x] = woff + sc;
}

// exclusive scan of block sums (nb <= 256); bsum[nb] = grand total
__global__ __launch_bounds__(256) void k_scan_top(int* __restrict__ bsum, int nb) {
  __shared__ int sm[256];
  const int tid = threadIdx.x;
  int v = (tid < nb) ? bsum[tid] : 0;
  sm[tid] = v;
  __syncthreads();
  for (int off = 1; off < 256; off <<= 1) {
    int t = (tid >= off) ? sm[tid - off] : 0;
    __syncthreads();
    sm[tid] += t;
    __syncthreads();
  }
  int incl = sm[tid];
  if (tid < nb) bsum[tid] = incl - v;
  if (tid == nb - 1) bsum[nb] = incl;
}

__global__ void k_scan_add(int* __restrict__ rowp, const int* __restrict__ bsum,
                           int n, int nb) {
  int i = blockIdx.x * blockDim.x + threadIdx.x;
  if (i < n) rowp[i] += bsum[i >> 10];
  if (i == 0) rowp[n] = bsum[nb];
}

__global__ void k_fill(const int* __restrict__ src, const int* __restrict__ dst,
                       const int* __restrict__ rowp, int* __restrict__ cur,
                       int* __restrict__ colsrc, int E) {
  int i = blockIdx.x * blockDim.x + threadIdx.x;
  if (i < E) {
    int d = dst[i];
    int pos = rowp[d] + atomicAdd(&cur[d], 1);
    colsrc[pos] = src[i];
  }
}

// ---------------- one-time splits ----------------
__global__ void k_splitx(const float* __restrict__ x, unsigned short* __restrict__ xh,
                         unsigned short* __restrict__ xl, long n) {
  long i = (long)blockIdx.x * blockDim.x + threadIdx.x;
  if (i < n) {
    float v = x[i];
    unsigned short h = f2bf_rn(v);
    xh[i] = h;
    xl[i] = f2bf_rn(v - bf2f(h));
  }
}

// all weights -> transposed hi/lo planes, one launch
__global__ void k_splitw_all(const float* __restrict__ Win, const float* __restrict__ Wg1,
                             const float* __restrict__ Wg2, const float* __restrict__ Wgat,
                             const float* __restrict__ Wao, const float* __restrict__ Wout,
                             unsigned short* __restrict__ WinTh, unsigned short* __restrict__ WinTl,
                             unsigned short* __restrict__ Wg1Th, unsigned short* __restrict__ Wg1Tl,
                             unsigned short* __restrict__ Wg2Th, unsigned short* __restrict__ Wg2Tl,
                             unsigned short* __restrict__ WgatTh, unsigned short* __restrict__ WgatTl,
                             unsigned short* __restrict__ WaoTh, unsigned short* __restrict__ WaoTl,
                             unsigned short* __restrict__ WoutTh, unsigned short* __restrict__ WoutTl) {
  int t = blockIdx.x * blockDim.x + threadIdx.x;
  const float* W;
  unsigned short *H, *L;
  int K, NC, r;
  if (t < 32768)       { W = Win;  H = WinTh;  L = WinTl;  K = 256; NC = 128; r = t; }
  else if (t < 49152)  { W = Wg1;  H = Wg1Th;  L = Wg1Tl;  K = 128; NC = 128; r = t - 32768; }
  else if (t < 65536)  { W = Wg2;  H = Wg2Th;  L = Wg2Tl;  K = 128; NC = 128; r = t - 49152; }
  else if (t < 131072) { W = Wgat; H = WgatTh; L = WgatTl; K = 128; NC = 512; r = t - 65536; }
  else if (t < 196608) { W = Wao;  H = WaoTh;  L = WaoTl;  K = 512; NC = 128; r = t - 131072; }
  else if (t < 204800) { W = Wout; H = WoutTh; L = WoutTl; K = 128; NC = 64;  r = t - 196608; }
  else return;
  int k = r / NC, n2 = r % NC;
  float v = W[r];
  unsigned short h = f2bf_rn(v);
  H[(size_t)n2 * K + k] = h;
  L[(size_t)n2 * K + k] = f2bf_rn(v - bf2f(h));
}

// ---------------- MFMA GEMM, pre-split planes, dbuf global_load_lds, BM=64 ----------------
// C = act(A @ W + bias); A as (Ah,Al)[M,K], W as (BhT,BlT)[NC,K].
// A*B ~= Ah*Bh + Ah*Bl + Al*Bh. 4 waves 2x2 (wave tile 32 x WCF*16).
// OUTM: 0=f32, 1=bf16, 2=hi/lo planes
template <int BN, int WCF, bool RELU, bool BIAS, int OUTM>
__global__ __launch_bounds__(256) void k_gemm3(
    const unsigned short* __restrict__ Ah, const unsigned short* __restrict__ Al,
    const unsigned short* __restrict__ BhT, const unsigned short* __restrict__ BlT,
    const float* __restrict__ bias, void* __restrict__ Cv, void* __restrict__ Cv2,
    int M, int K, int NC) {
  constexpr int BM = 64;
  constexpr int RUNS = 8 + 8 * (BN / 64);
  __shared__ alignas(16) unsigned short As[2][2][4][BM][8];
  __shared__ alignas(16) unsigned short Bs[2][2][4][BN][8];
  const int tid = threadIdx.x;
  const int lane = tid & 63;
  const int wid = tid >> 6;
  const int wr = wid >> 1, wc = wid & 1;
  const int m0 = blockIdx.x * BM;
  const int n0 = blockIdx.y * BN;
  const int fr = lane & 15, g = lane >> 4;
  const bool arow_ok = (m0 + lane) < M;

  f32x4 acc[2][WCF];
#pragma unroll
  for (int mr = 0; mr < 2; ++mr)
#pragma unroll
    for (int nc = 0; nc < WCF; ++nc) acc[mr][nc] = (f32x4){0.f, 0.f, 0.f, 0.f};

  const unsigned short* aPl[2] = {Ah, Al};
  const unsigned short* bPl[2] = {BhT, BlT};

#define STAGE(d, kk)                                                                 \
  for (int rr = wid; rr < RUNS; rr += 4) {                                           \
    if (rr < 8) {                                                                    \
      const int p = rr & 1, kg = rr >> 1;                                            \
      const unsigned short* sp = aPl[p] + (size_t)(m0 + lane) * K + (kk) + kg * 8;   \
      if (arow_ok) GLD16(sp, &As[d][p][kg][0][0]);                                   \
    } else {                                                                         \
      const int q = rr - 8;                                                          \
      const int p = q & 1, kg = (q >> 1) & 3, cb = q >> 3;                           \
      const unsigned short* sp =                                                     \
          bPl[p] + (size_t)(n0 + cb * 64 + lane) * K + (kk) + kg * 8;                \
      GLD16(sp, &Bs[d][p][kg][cb * 64][0]);                                          \
    }                                                                                \
  }

  STAGE(0, 0)
  __syncthreads();
  int cur = 0;
  for (int k0 = 0; k0 < K; k0 += 32) {
    if (k0 + 32 < K) { STAGE(cur ^ 1, k0 + 32) }
    bf16x8 ah[2], al[2], bh[WCF], bl[WCF];
#pragma unroll
    for (int mr = 0; mr < 2; ++mr) {
      const int row = wr * 32 + mr * 16 + fr;
      ah[mr] = *(const bf16x8*)&As[cur][0][g][row][0];
      al[mr] = *(const bf16x8*)&As[cur][1][g][row][0];
    }
#pragma unroll
    for (int nc = 0; nc < WCF; ++nc) {
      const int col = wc * WCF * 16 + nc * 16 + fr;
      bh[nc] = *(const bf16x8*)&Bs[cur][0][g][col][0];
      bl[nc] = *(const bf16x8*)&Bs[cur][1][g][col][0];
    }
#pragma unroll
    for (int mr = 0; mr < 2; ++mr)
#pragma unroll
      for (int nc = 0; nc < WCF; ++nc) {
        acc[mr][nc] = __builtin_amdgcn_mfma_f32_16x16x32_bf16(ah[mr], bh[nc], acc[mr][nc], 0, 0, 0);
        acc[mr][nc] = __builtin_amdgcn_mfma_f32_16x16x32_bf16(ah[mr], bl[nc], acc[mr][nc], 0, 0, 0);
        acc[mr][nc] = __builtin_amdgcn_mfma_f32_16x16x32_bf16(al[mr], bh[nc], acc[mr][nc], 0, 0, 0);
      }
    __syncthreads();
    cur ^= 1;
  }
#undef STAGE
  // ---- epilogue ----
#pragma unroll
  for (int mr = 0; mr < 2; ++mr) {
#pragma unroll
    for (int nc = 0; nc < WCF; ++nc) {
      const int col = n0 + wc * WCF * 16 + nc * 16 + fr;
      const float bv = BIAS ? bias[col] : 0.f;
#pragma unroll
      for (int r = 0; r < 4; ++r) {
        const int grow = m0 + wr * 32 + mr * 16 + g * 4 + r;
        if (grow < M) {
          float v = acc[mr][nc][r] + bv;
          if (RELU) v = fmaxf(v, 0.f);
          const size_t idx = (size_t)grow * NC + col;
          if (OUTM == 0) {
            ((float*)Cv)[idx] = v;
          } else if (OUTM == 1) {
            ((unsigned short*)Cv)[idx] = f2bf_rn(v);
          } else {
            unsigned short h = f2bf_rn(v);
            ((unsigned short*)Cv)[idx] = h;
            ((unsigned short*)Cv2)[idx] = f2bf_rn(v - bf2f(h));
          }
        }
      }
    }
  }
}

// ---------------- GCN aggregate + bias + LN + ReLU (+residual, +fused GAT logits) ----------------
template <bool L2>
__global__ __launch_bounds__(256) void k_gcn_agg(
    const float* __restrict__ xw, const float* __restrict__ dinv,
    const int* __restrict__ rowp, const int* __restrict__ colsrc,
    const float* __restrict__ bias, const float* __restrict__ gamma,
    const float* __restrict__ beta,
    const unsigned short* __restrict__ resh, const unsigned short* __restrict__ resl,
    unsigned short* __restrict__ oh, unsigned short* __restrict__ ol,
    const float* __restrict__ waT, float* __restrict__ a_s, float* __restrict__ a_d,
    int n) {
  __shared__ float w[8][HID];
  if (L2) {
    for (int t = threadIdx.x; t < 8 * HID; t += 256) ((float*)w)[t] = waT[t];
    __syncthreads();
  }
  const int lane = threadIdx.x & 63;
  const int i = blockIdx.x * 4 + (threadIdx.x >> 6);
  if (i >= n) return;
  const float di = dinv[i];
  const int c = lane * 2;
  float2 v = *(const float2*)(xw + (size_t)i * HID + c);
  float a0 = v.x * di * di, a1 = v.y * di * di;  // self loop
  const int e0 = rowp[i], e1 = rowp[i + 1];
  for (int j = e0; j < e1; ++j) {
    int s = colsrc[j];
    float wgt = dinv[s] * di;
    float2 u = *(const float2*)(xw + (size_t)s * HID + c);
    a0 = fmaf(u.x, wgt, a0);
    a1 = fmaf(u.y, wgt, a1);
  }
  a0 += bias[c];
  a1 += bias[c + 1];
  float s1 = a0 + a1, s2 = a0 * a0 + a1 * a1;
#pragma unroll
  for (int m = 32; m >= 1; m >>= 1) {
    s1 += __shfl_xor(s1, m);
    s2 += __shfl_xor(s2, m);
  }
  float mu = s1 * (1.0f / HID);
  float var = s2 * (1.0f / HID) - mu * mu;
  float rstd = rsqrtf(var + 1e-5f);
  float y0 = fmaxf((a0 - mu) * rstd * gamma[c] + beta[c], 0.0f);
  float y1 = fmaxf((a1 - mu) * rstd * gamma[c + 1] + beta[c + 1], 0.0f);
  if (L2) {
    uint32_t rh = *(const uint32_t*)(resh + (size_t)i * HID + c);
    uint32_t rl = *(const uint32_t*)(resl + (size_t)i * HID + c);
    y0 += bflo(rh) + bflo(rl);
    y1 += bfhi(rh) + bfhi(rl);
  }
  unsigned short ph0 = f2bf_rn(y0), ph1 = f2bf_rn(y1);
  uint32_t hw = (uint32_t)ph0 | ((uint32_t)ph1 << 16);
  uint32_t lw = (uint32_t)f2bf_rn(y0 - bf2f(ph0)) |
                ((uint32_t)f2bf_rn(y1 - bf2f(ph1)) << 16);
  *(uint32_t*)(oh + (size_t)i * HID + c) = hw;
  *(uint32_t*)(ol + (size_t)i * HID + c) = lw;
  if (L2) {
    float p[8];
#pragma unroll
    for (int h = 0; h < 8; ++h) p[h] = y0 * w[h][c] + y1 * w[h][c + 1];
#pragma unroll
    for (int m = 32; m >= 1; m >>= 1) {
#pragma unroll
      for (int h = 0; h < 8; ++h) p[h] += __shfl_xor(p[h], m);
    }
    if (lane == 0) {
      a_s[i * 4 + 0] = p[0]; a_s[i * 4 + 1] = p[1];
      a_s[i * 4 + 2] = p[2]; a_s[i * 4 + 3] = p[3];
      a_d[i * 4 + 0] = p[4]; a_d[i * 4 + 1] = p[5];
      a_d[i * 4 + 2] = p[6]; a_d[i * 4 + 3] = p[7];
    }
  }
}

// ---------------- fold Wgat into attention vectors ----------------
__global__ __launch_bounds__(256) void k_wprep(const float* __restrict__ Wgat,
                                               const float* __restrict__ att_src,
                                               const float* __restrict__ att_dst,
                                               float* __restrict__ waT) {
  int t = blockIdx.x * blockDim.x + threadIdx.x;  // 0..1023
  if (t >= 1024) return;
  int p = t >> 7, k = t & 127;
  int h = p & 3;
  const float* av = (p < 4 ? att_src : att_dst) + h * HID;
  const float* wrow = Wgat + (size_t)k * GATD + h * HID;
  float s = 0.f;
#pragma unroll 4
  for (int c = 0; c < HID; ++c) s = fmaf(wrow[c], av[c], s);
  waT[t] = s;
}

// ---------------- GAT softmax-aggregate (wave/node), bf16 table, plane output ----------------
__global__ __launch_bounds__(256) void k_gat_agg(const unsigned short* __restrict__ xwgb,
                                                 const float* __restrict__ a_s,
                                                 const float* __restrict__ a_d,
                                                 const int* __restrict__ rowp,
                                                 const int* __restrict__ colsrc,
                                                 const float* __restrict__ bias,
                                                 unsigned short* __restrict__ gath,
                                                 unsigned short* __restrict__ gatl,
                                                 int n) {
  const int lane = threadIdx.x & 63;
  const int i = blockIdx.x * 4 + (threadIdx.x >> 6);
  if (i >= n) return;
  const float4 adv = *(const float4*)(a_d + i * 4);
  const float4 asv = *(const float4*)(a_s + i * 4);
  float es0 = lrelu02(asv.x + adv.x);
  float es1 = lrelu02(asv.y + adv.y);
  float es2 = lrelu02(asv.z + adv.z);
  float es3 = lrelu02(asv.w + adv.w);
  const int e0 = rowp[i], e1 = rowp[i + 1];
  float m0 = es0, m1 = es1, m2 = es2, m3 = es3;
  for (int j = e0 + lane; j < e1; j += 64) {
    int s = colsrc[j];
    const float4 av = *(const float4*)(a_s + s * 4);
    m0 = fmaxf(m0, lrelu02(av.x + adv.x));
    m1 = fmaxf(m1, lrelu02(av.y + adv.y));
    m2 = fmaxf(m2, lrelu02(av.z + adv.z));
    m3 = fmaxf(m3, lrelu02(av.w + adv.w));
  }
#pragma unroll
  for (int m = 32; m >= 1; m >>= 1) {
    m0 = fmaxf(m0, __shfl_xor(m0, m));
    m1 = fmaxf(m1, __shfl_xor(m1, m));
    m2 = fmaxf(m2, __shfl_xor(m2, m));
    m3 = fmaxf(m3, __shfl_xor(m3, m));
  }
  float d0 = 0.f, d1 = 0.f, d2 = 0.f, d3 = 0.f;
  for (int j = e0 + lane; j < e1; j += 64) {
    int s = colsrc[j];
    const float4 av = *(const float4*)(a_s + s * 4);
    d0 += __expf(lrelu02(av.x + adv.x) - m0);
    d1 += __expf(lrelu02(av.y + adv.y) - m1);
    d2 += __expf(lrelu02(av.z + adv.z) - m2);
    d3 += __expf(lrelu02(av.w + adv.w) - m3);
  }
#pragma unroll
  for (int m = 32; m >= 1; m >>= 1) {
    d0 += __shfl_xor(d0, m);
    d1 += __shfl_xor(d1, m);
    d2 += __shfl_xor(d2, m);
    d3 += __shfl_xor(d3, m);
  }
  d0 += __expf(es0 - m0);
  d1 += __expf(es1 - m1);
  d2 += __expf(es2 - m2);
  d3 += __expf(es3 - m3);
  const float inv0 = 1.0f / d0, inv1 = 1.0f / d1, inv2 = 1.0f / d2, inv3 = 1.0f / d3;
  const int col = lane * 8;
  const int h = lane >> 4;
  const float mh = (h < 2) ? (h == 0 ? m0 : m1) : (h == 2 ? m2 : m3);
  const float invh = (h < 2) ? (h == 0 ? inv0 : inv1) : (h == 2 ? inv2 : inv3);
  const float adh = (h < 2) ? (h == 0 ? adv.x : adv.y) : (h == 2 ? adv.z : adv.w);
  const float esh = (h < 2) ? (h == 0 ? es0 : es1) : (h == 2 ? es2 : es3);
  const float aself = __expf(esh - mh) * invh;
  uint4 u = *(const uint4*)(xwgb + (size_t)i * GATD + col);
  float4 acc0 = make_float4(bflo(u.x) * aself, bfhi(u.x) * aself,
                            bflo(u.y) * aself, bfhi(u.y) * aself);
  float4 acc1 = make_float4(bflo(u.z) * aself, bfhi(u.z) * aself,
                            bflo(u.w) * aself, bfhi(u.w) * aself);
  for (int j = e0; j < e1; ++j) {
    int s = colsrc[j];
    float al = __expf(lrelu02(a_s[s * 4 + h] + adh) - mh) * invh;
    uint4 w = *(const uint4*)(xwgb + (size_t)s * GATD + col);
    acc0.x = fmaf(bflo(w.x), al, acc0.x); acc0.y = fmaf(bfhi(w.x), al, acc0.y);
    acc0.z = fmaf(bflo(w.y), al, acc0.z); acc0.w = fmaf(bfhi(w.y), al, acc0.w);
    acc1.x = fmaf(bflo(w.z), al, acc1.x); acc1.y = fmaf(bfhi(w.z), al, acc1.y);
    acc1.z = fmaf(bflo(w.w), al, acc1.z); acc1.w = fmaf(bfhi(w.w), al, acc1.w);
  }
  const float4* bp = (const float4*)(bias + col);
  float4 b0 = bp[0], b1 = bp[1];
  float vv[8] = {acc0.x + b0.x, acc0.y + b0.y, acc0.z + b0.z, acc0.w + b0.w,
                 acc1.x + b1.x, acc1.y + b1.y, acc1.z + b1.z, acc1.w + b1.w};
  uint32_t hv[4], lv[4];
#pragma unroll
  for (int q = 0; q < 4; ++q) {
    unsigned short ha = f2bf_rn(vv[2 * q]), hb = f2bf_rn(vv[2 * q + 1]);
    unsigned short la = f2bf_rn(vv[2 * q] - bf2f(ha));
    unsigned short lb = f2bf_rn(vv[2 * q + 1] - bf2f(hb));
    hv[q] = (uint32_t)ha | ((uint32_t)hb << 16);
    lv[q] = (uint32_t)la | ((uint32_t)lb << 16);
  }
  *(uint4*)(gath + (size_t)i * GATD + col) = make_uint4(hv[0], hv[1], hv[2], hv[3]);
  *(uint4*)(gatl + (size_t)i * GATD + col) = make_uint4(lv[0], lv[1], lv[2], lv[3]);
}

extern "C" void kernel_launch(void* const* d_in, const int* in_sizes, int n_in,
                              void* d_out, int out_size, void* d_ws, size_t ws_size,
                              hipStream_t stream) {
  const float* x = (const float*)d_in[0];
  const int* ei = (const int*)d_in[1];
  const float* Win = (const float*)d_in[2];
  const float* bin = (const float*)d_in[3];
  const float* Wg1 = (const float*)d_in[4];
  const float* bg1 = (const float*)d_in[5];
  const float* g1g = (const float*)d_in[6];
  const float* g1b = (const float*)d_in[7];
  const float* Wg2 = (const float*)d_in[8];
  const float* bg2 = (const float*)d_in[9];
  const float* g2g = (const float*)d_in[10];
  const float* g2b = (const float*)d_in[11];
  const float* Wgat = (const float*)d_in[12];
  const float* att_s = (const float*)d_in[13];
  const float* att_d = (const float*)d_in[14];
  const float* bgat = (const float*)d_in[15];
  const float* Wao = (const float*)d_in[16];
  const float* bao = (const float*)d_in[17];
  const float* Wout = (const float*)d_in[18];
  const float* bout = (const float*)d_in[19];

  const int N = in_sizes[0] / 256;
  const int E = in_sizes[1] / 2;
  const int* src = ei;
  const int* dst = ei + E;

  // ---- workspace layout (bytes), ~211 MB ----
  char* base = (char*)d_ws;
  size_t off = 0;
  unsigned short* xh = (unsigned short*)(base + off);  off += (size_t)N * 256 * 2;
  unsigned short* xl = (unsigned short*)(base + off);  off += (size_t)N * 256 * 2;
  unsigned short* h0h = (unsigned short*)(base + off); off += (size_t)N * HID * 2;
  unsigned short* h0l = (unsigned short*)(base + off); off += (size_t)N * HID * 2;
  unsigned short* x1h = (unsigned short*)(base + off); off += (size_t)N * HID * 2;
  unsigned short* x1l = (unsigned short*)(base + off); off += (size_t)N * HID * 2;
  unsigned short* gath = xh;   // dead by GAT agg
  unsigned short* gatl = h0h;  // dead by GAT agg
  float* xw = (float*)(base + off);                    off += (size_t)N * HID * 4;
  unsigned short* x2h = (unsigned short*)(base + off); off += (size_t)N * HID * 2;
  unsigned short* x2l = (unsigned short*)(base + off); off += (size_t)N * HID * 2;
  unsigned short* atth = x2h;  // reuse after Wgat GEMM
  unsigned short* attl = x2l;
  unsigned short* xwgb = (unsigned short*)(base + off); off += (size_t)N * GATD * 2;
  float* dinv = (float*)(base + off);                  off += (size_t)N * 4;
  float* a_s = (float*)(base + off);                   off += (size_t)N * 16;
  float* a_d = (float*)(base + off);                   off += (size_t)N * 16;
  float* waT = (float*)(base + off);                   off += 4096;
  unsigned short *WinTh, *WinTl, *Wg1Th, *Wg1Tl, *Wg2Th, *Wg2Tl;
  unsigned short *WgatTh, *WgatTl, *WaoTh, *WaoTl, *WoutTh, *WoutTl;
  WinTh = (unsigned short*)(base + off);  off += 256 * 128 * 2;
  WinTl = (unsigned short*)(base + off);  off += 256 * 128 * 2;
  Wg1Th = (unsigned short*)(base + off);  off += 128 * 128 * 2;
  Wg1Tl = (unsigned short*)(base + off);  off += 128 * 128 * 2;
  Wg2Th = (unsigned short*)(base + off);  off += 128 * 128 * 2;
  Wg2Tl = (unsigned short*)(base + off);  off += 128 * 128 * 2;
  WgatTh = (unsigned short*)(base + off); off += 128 * 512 * 2;
  WgatTl = (unsigned short*)(base + off); off += 128 * 512 * 2;
  WaoTh = (unsigned short*)(base + off);  off += 512 * 128 * 2;
  WaoTl = (unsigned short*)(base + off);  off += 512 * 128 * 2;
  WoutTh = (unsigned short*)(base + off); off += 128 * 64 * 2;
  WoutTl = (unsigned short*)(base + off); off += 128 * 64 * 2;
  int* rowp = (int*)(base + off);   off += (size_t)(N + 1) * 4;
  int* colsrc = (int*)(base + off); off += (size_t)E * 4;
  const int nb2 = (N + 1023) / 1024;
  int* bsum = (int*)(base + off);   off += (size_t)(nb2 + 2) * 4;
  int* cnt = (int*)xwgb;  // alias: dead before xwgb is written
  int* cur = cnt + N;

  const int eb = (E + TPB - 1) / TPB;
  const int zb = (2 * N + TPB - 1) / TPB;
  const int ab = (N + 3) / 4;
  const int gm = (N + 63) / 64;

  // CSR + prep
  k_zero<<<zb, TPB, 0, stream>>>(cnt, 2 * N);
  k_hist<<<eb, TPB, 0, stream>>>(dst, cnt, E);
  k_scan_blk<<<nb2, 256, 0, stream>>>(cnt, rowp, bsum, dinv, N);
  k_scan_top<<<1, 256, 0, stream>>>(bsum, nb2);
  k_scan_add<<<(N + 255) / 256, 256, 0, stream>>>(rowp, bsum, N, nb2);
  k_fill<<<eb, TPB, 0, stream>>>(src, dst, rowp, cur, colsrc, E);
  k_wprep<<<4, 256, 0, stream>>>(Wgat, att_s, att_d, waT);
  k_splitx<<<(int)(((long)N * 256 + 255) / 256), 256, 0, stream>>>(x, xh, xl, (long)N * 256);
  k_splitw_all<<<(204800 + 255) / 256, 256, 0, stream>>>(
      Win, Wg1, Wg2, Wgat, Wao, Wout, WinTh, WinTl, Wg1Th, Wg1Tl, Wg2Th, Wg2Tl,
      WgatTh, WgatTl, WaoTh, WaoTl, WoutTh, WoutTl);

  // h0 = relu(x @ Win + bin) -> planes
  k_gemm3<128, 4, true, true, 2><<<dim3(gm, 1), 256, 0, stream>>>(
      xh, xl, WinTh, WinTl, bin, h0h, h0l, N, 256, 128);
  // GCN layer 1
  k_gemm3<128, 4, false, false, 0><<<dim3(gm, 1), 256, 0, stream>>>(
      h0h, h0l, Wg1Th, Wg1Tl, nullptr, xw, nullptr, N, 128, 128);
  k_gcn_agg<false><<<ab, 256, 0, stream>>>(xw, dinv, rowp, colsrc, bg1, g1g, g1b,
                                           nullptr, nullptr, x1h, x1l,
                                           nullptr, nullptr, nullptr, N);
  // GCN layer 2 (+residual, +fused GAT logits)
  k_gemm3<128, 4, false, false, 0><<<dim3(gm, 1), 256, 0, stream>>>(
      x1h, x1l, Wg2Th, Wg2Tl, nullptr, xw, nullptr, N, 128, 128);
  k_gcn_agg<true><<<ab, 256, 0, stream>>>(xw, dinv, rowp, colsrc, bg2, g2g, g2b,
                                          x1h, x1l, x2h, x2l, waT, a_s, a_d, N);
  // GAT: xwgb = bf16(x2 @ Wgat)
  k_gemm3<128, 4, false, false, 1><<<dim3(gm, 4), 256, 0, stream>>>(
      x2h, x2l, WgatTh, WgatTl, nullptr, xwgb, nullptr, N, 128, 512);
  // softmax-aggregate -> gat planes
  k_gat_agg<<<ab, 256, 0, stream>>>(xwgb, a_s, a_d, rowp, colsrc, bgat, gath, gatl, N);
  // att = relu(gat @ Wao + bao) -> planes
  k_gemm3<128, 4, true, true, 2><<<dim3(gm, 1), 256, 0, stream>>>(
      gath, gatl, WaoTh, WaoTl, bao, atth, attl, N, 512, 128);
  // out = att @ Wout + bout (fp32)
  k_gemm3<64, 2, false, true, 0><<<dim3(gm, 1), 256, 0, stream>>>(
      atth, attl, WoutTh, WoutTl, bout, d_out, nullptr, N, 128, 64);
}